// Round 2
// baseline (202.450 us; speedup 1.0000x reference)
//
#include <hip/hip_runtime.h>
#include <stdint.h>

// FactorLayer: B=4096, D=4096, T=16, all float32.
// Math: X = znorm(inputs); Y = X@W_static; Z = X@W.
// All deflations use the ORIGINAL X => conv_j is fixed once born; every c_i and
// output column lives in span{Y0..Y15, ones}. The sequential scan collapses to
// 17-dim coefficient recurrences on the 33x33 Gram of [Y|Z|1];
// Out = Z - [Y|1] @ Wmat (17x16).

#define BB 4096
#define DD 4096
#define T2 32
#define EPSF 1e-6f

// ws layout (float indices)
#define O_COLSUM   0u
#define O_COLSQ    4096u
#define O_MU       8192u
#define O_INV      12288u
#define O_WSF      16384u        // 131072 floats: [d][32]; t<16: W_static (->Y), t>=16: W (->Z)
#define O_GRAM     147456u       // 33*33 = 1089
#define O_WMAT     148552u       // 17*16 = 272
#define O_YZ       148992u       // 4096*32 floats (16B aligned)
#define O_YPART    280064u       // 32*4096*32 = 4194304 floats  (ws total ~17.9 MiB)

// ---------------- K0: zero the accumulators (ws is poisoned 0xAA) -----------
__global__ void k0_zero(float* __restrict__ ws) {
    int tid = blockIdx.x * 256 + threadIdx.x;
    if (tid < 8192) ws[tid] = 0.f;              // colsum + colsumsq
    int g = tid - 8192;
    if (g >= 0 && g < 1089) ws[O_GRAM + g] = 0.f;
}

// ---------------- K1: per-column sum / sumsq ---------------------------------
__global__ void k1_stats(const float* __restrict__ in, float* __restrict__ ws) {
    int dg = blockIdx.x & 3;           // 4 column groups of 1024
    int rg = blockIdx.x >> 2;          // 64 row groups of 64
    int c0 = dg * 1024 + threadIdx.x * 4;
    int r0 = rg * 64;
    float s0=0.f,s1=0.f,s2=0.f,s3=0.f,q0=0.f,q1=0.f,q2=0.f,q3=0.f;
    for (int r = 0; r < 64; ++r) {
        float4 u = *(const float4*)&in[(size_t)(r0 + r) * DD + c0];
        s0 += u.x; q0 += u.x*u.x;  s1 += u.y; q1 += u.y*u.y;
        s2 += u.z; q2 += u.z*u.z;  s3 += u.w; q3 += u.w*u.w;
    }
    float* colsum = ws + O_COLSUM;
    float* colsq  = ws + O_COLSQ;
    atomicAdd(&colsum[c0+0], s0); atomicAdd(&colsum[c0+1], s1);
    atomicAdd(&colsum[c0+2], s2); atomicAdd(&colsum[c0+3], s3);
    atomicAdd(&colsq[c0+0], q0);  atomicAdd(&colsq[c0+1], q1);
    atomicAdd(&colsq[c0+2], q2);  atomicAdd(&colsq[c0+3], q3);
}

// ---------------- K2: mu, 1/(std+eps); weights -> [d][32] --------------------
__global__ void k2_prep(const float* __restrict__ W,
                        const float* __restrict__ Wstat,
                        float* __restrict__ ws) {
    int tid = blockIdx.x * 256 + threadIdx.x;
    if (tid < DD * T2) {
        int d = tid >> 5, t = tid & 31;
        ws[O_WSF + tid] = (t < 16) ? Wstat[d * 16 + t] : W[d * 16 + (t - 16)];
    }
    if (tid < DD) {
        float m  = ws[O_COLSUM + tid] * (1.0f / BB);
        float e2 = ws[O_COLSQ  + tid] * (1.0f / BB);
        float var = e2 - m * m; if (var < 0.f) var = 0.f;
        ws[O_MU  + tid] = m;
        ws[O_INV + tid] = 1.0f / (sqrtf(var) + EPSF);
    }
}

// ---------------- K3: skinny GEMM -> ypart[dg][b][32] (partial over 128 d) ---
// 512 blocks = 16 rowgroups(256 rows) x 32 dgroups(128 d). thread <-> row.
// X staged through LDS with stride 33 (scalar b32 reads: conflict-free;
// 64 lanes / 32 banks 2-way aliasing is free). Weights wave-uniform -> s_load.
__global__ __launch_bounds__(256, 2)
void k3_gemm(const float* __restrict__ in, const float* __restrict__ ws,
             float* __restrict__ ypart) {
    __shared__ float tile[256 * 33];          // 33.8 KB -> 2 blocks/CU
    int dg = blockIdx.x & 31;
    int rg = blockIdx.x >> 5;
    int dbase = dg * 128;
    int rowbase = rg * 256;
    int t = threadIdx.x;
    const float* mu  = ws + O_MU;
    const float* inv = ws + O_INV;
    const float* wsf = ws + O_WSF;
    float acc[32];
    #pragma unroll
    for (int i = 0; i < 32; ++i) acc[i] = 0.f;

    int c = t & 7, rr = t >> 3;               // staging role: float4 chunk, row
    for (int stage = 0; stage < 4; ++stage) {
        int ds0 = dbase + stage * 32;
        #pragma unroll
        for (int s = 0; s < 8; ++s) {         // 8 sweeps x 32 rows
            int row = s * 32 + rr;
            float4 u = *(const float4*)&in[(size_t)(rowbase + row) * DD + ds0 + c * 4];
            int base = row * 33 + c * 4;
            tile[base + 0] = u.x; tile[base + 1] = u.y;
            tile[base + 2] = u.z; tile[base + 3] = u.w;
        }
        __syncthreads();
        const float* trow = tile + t * 33;
        #pragma unroll 4
        for (int dl = 0; dl < 32; ++dl) {
            int d = ds0 + dl;                 // wave-uniform
            float xs = (trow[dl] - mu[d]) * inv[d];
            const float* wr = wsf + (size_t)d * 32;
            #pragma unroll
            for (int j = 0; j < 32; ++j) acc[j] += xs * wr[j];
        }
        __syncthreads();
    }
    float* dst = ypart + ((size_t)dg * BB + rowbase + t) * 32;
    #pragma unroll
    for (int j = 0; j < 32; j += 4)
        *(float4*)(dst + j) = make_float4(acc[j], acc[j+1], acc[j+2], acc[j+3]);
}

// ---------------- K4: reduce partials -> YZ; accumulate 33x33 Gram -----------
__global__ void k4_reduce_gram(float* __restrict__ ws) {
    __shared__ float yz_s[16 * 34];
    int t = threadIdx.x;
    int rowbase = blockIdx.x * 16;            // 256 blocks x 16 rows
    const float* ypart = ws + O_YPART;
    float* yz   = ws + O_YZ;
    float* gram = ws + O_GRAM;
    for (int sweep = 0; sweep < 2; ++sweep) {
        int r  = sweep * 8 + (t >> 5);
        int tt = t & 31;
        size_t off = (size_t)(rowbase + r) * 32 + tt;
        float s = 0.f;
        for (int dg = 0; dg < 32; ++dg) s += ypart[(size_t)dg * BB * 32 + off];
        yz[off] = s;
        yz_s[r * 34 + tt] = s;
        if (tt == 0) yz_s[r * 34 + 32] = 1.0f;
    }
    __syncthreads();
    for (int p = t; p < 561; p += 256) {      // upper-tri pairs (i<=j<=32)
        int i = 0, rem = p;
        while (rem >= 33 - i) { rem -= 33 - i; ++i; }
        int j = i + rem;
        float s = 0.f;
        for (int r = 0; r < 16; ++r) s += yz_s[r * 34 + i] * yz_s[r * 34 + j];
        atomicAdd(&gram[i * 33 + j], s);
        if (i != j) atomicAdd(&gram[j * 33 + i], s);
    }
}

// ---------------- K5: 17-dim sequential recurrences -> Wmat (17x16) ----------
// Basis p=0..15 -> Y[:,p], p=16 -> ones. Gram idx: Y->p, Z_t->16+t, ones->32.
__global__ void k5_seq(float* __restrict__ ws) {
    __shared__ float GA[17 * 17], gz[17 * 16], v[15][17], gad[15][16], gzd[15][16],
                     gu[17], u[17], st[2];
    int t = threadIdx.x;                      // 64 threads
    const float* gram = ws + O_GRAM;
    for (int idx = t; idx < 17 * 17; idx += 64) {
        int p = idx / 17, q = idx % 17;
        int mp = p < 16 ? p : 32, mq = q < 16 ? q : 32;
        GA[idx] = gram[mp * 33 + mq];
    }
    for (int idx = t; idx < 17 * 16; idx += 64) {
        int p = idx / 16, tt = idx % 16;
        int mp = p < 16 ? p : 32;
        gz[idx] = gram[mp * 33 + 16 + tt];
    }
    if (t < 17) u[t] = (t == 0) ? 1.f : 0.f;
    __syncthreads();
    const float invB = 1.0f / BB;
    for (int i = 0; i < 15; ++i) {
        if (t < 17) {                         // gu = GA @ u
            float s = 0.f;
            for (int q = 0; q < 17; ++q) s += GA[t * 17 + q] * u[q];
            gu[t] = s;
        }
        __syncthreads();
        if (t == 0) {                         // stats of c_i
            float mean = gu[16] * invB;
            float e2 = 0.f;
            for (int p = 0; p < 17; ++p) e2 += u[p] * gu[p];
            e2 *= invB;
            float var = e2 - mean * mean; if (var < 0.f) var = 0.f;
            st[0] = mean; st[1] = 1.0f / (sqrtf(var) + EPSF);
        }
        __syncthreads();
        if (t < 17) v[i][t] = (u[t] - (t == 16 ? st[0] : 0.f)) * st[1];
        __syncthreads();
        if (t < 16) {                         // gad[i][k] = conv_i . Y[:,k]
            float s = 0.f;
            for (int p = 0; p < 17; ++p) s += v[i][p] * GA[p * 17 + t];
            gad[i][t] = s;
        } else if (t < 32) {                  // gzd[i][t] = conv_i . Z[:,t]
            int tt = t - 16;
            float s = 0.f;
            for (int p = 0; p < 17; ++p) s += v[i][p] * gz[p * 16 + tt];
            gzd[i][tt] = s;
        }
        __syncthreads();
        if (t < 17) {                         // u_{i+1} = e_{i+1} - sum_j v_j * gad[j][i+1]/B
            float acc = 0.f;
            for (int j = 0; j <= i; ++j) acc += v[j][t] * gad[j][i + 1];
            u[t] = ((t == i + 1) ? 1.f : 0.f) - acc * invB;
        }
        __syncthreads();
    }
    float* wmat = ws + O_WMAT;
    for (int idx = t; idx < 17 * 16; idx += 64) {
        int p = idx / 16, tt = idx % 16;
        float s = 0.f;
        for (int j = 0; j < tt; ++j) s += v[j][p] * gzd[j][tt];
        wmat[idx] = s * invB;
    }
}

// ---------------- K6: Out[b][t] = Z[b][t] - [Y|1] @ Wmat ---------------------
__global__ void k6_out(const float* __restrict__ ws, float* __restrict__ out) {
    int b = blockIdx.x * 256 + threadIdx.x;
    const float* yz   = ws + O_YZ + (size_t)b * 32;
    const float* wmat = ws + O_WMAT;
    float y[16], z[16];
    #pragma unroll
    for (int j = 0; j < 16; j += 4) {
        float4 f = *(const float4*)(yz + j);
        y[j] = f.x; y[j+1] = f.y; y[j+2] = f.z; y[j+3] = f.w;
        float4 g = *(const float4*)(yz + 16 + j);
        z[j] = g.x; z[j+1] = g.y; z[j+2] = g.z; z[j+3] = g.w;
    }
    float o[16];
    #pragma unroll
    for (int tt = 0; tt < 16; ++tt) o[tt] = z[tt] - wmat[16 * 16 + tt];
    #pragma unroll
    for (int p = 0; p < 16; ++p) {
        float yp = y[p];
        #pragma unroll
        for (int tt = 0; tt < 16; ++tt) o[tt] -= yp * wmat[p * 16 + tt];
    }
    float* dst = out + (size_t)b * 16;
    #pragma unroll
    for (int j = 0; j < 16; j += 4)
        *(float4*)(dst + j) = make_float4(o[j], o[j+1], o[j+2], o[j+3]);
}

extern "C" void kernel_launch(void* const* d_in, const int* in_sizes, int n_in,
                              void* d_out, int out_size, void* d_ws, size_t ws_size,
                              hipStream_t stream) {
    const float* in    = (const float*)d_in[0];  // inputs (4096x4096) f32
    const float* W     = (const float*)d_in[1];  // W (4096x16) f32
    const float* Wstat = (const float*)d_in[2];  // W_static (4096x16) f32
    float* ws  = (float*)d_ws;
    float* out = (float*)d_out;

    k0_zero<<<dim3(37), dim3(256), 0, stream>>>(ws);
    k1_stats<<<dim3(256), dim3(256), 0, stream>>>(in, ws);
    k2_prep<<<dim3(512), dim3(256), 0, stream>>>(W, Wstat, ws);
    k3_gemm<<<dim3(512), dim3(256), 0, stream>>>(in, ws, ws + O_YPART);
    k4_reduce_gram<<<dim3(256), dim3(256), 0, stream>>>(ws);
    k5_seq<<<dim3(1), dim3(64), 0, stream>>>(ws);
    k6_out<<<dim3(16), dim3(256), 0, stream>>>(ws, out);
}

// Round 5
// 166.080 us; speedup vs baseline: 1.2190x; 1.2190x over previous
//
#include <hip/hip_runtime.h>
#include <stdint.h>

// FactorLayer: B=4096, D=4096, T=16, float32.
// X = znorm(inputs); Y = X@W_static; Z = X@W. All deflations use ORIGINAL X,
// so conv_j is fixed once born; everything lives in span{Y0..Y15, 1}.
// Sequential scan collapses to 17-dim recurrences on the Gram of [Y|Z|1];
// Out = Z - [Y|1] @ Wmat (17x16).  4 plain launches.
// R3: cooperative launch silently no-ops in this harness (output all zeros).
// R4: NaN — barrier-free wave-sync solve + unaligned float4 LDS reads were the
//     two untested mechanisms; both removed here (barriers restored, align(16)).

#define BB 4096
#define DD 4096
#define EPSF 1e-6f

// ws layout (float indices), ~22 MB total (ws is 256 MiB per R2 fill counters)
#define O_PART    0u          // [128 rowgroups][8192]: colsum(0..4095), colsq(4096..8191)
#define O_WSF     1048576u    // [d][32]: j<16 -> W_static (Y), j>=16 -> W (Z)
#define O_GRAMM   1179648u    // 8 copies x 1120 (33x33, upper-tri used)
#define O_YZ      1188608u    // [4096][32]  (byte offset 16B-aligned)
#define O_YPART   1319680u    // [32 dgroups][4096][32]

__device__ __forceinline__ int gidx(int a, int b) {   // upper-tri gram index
    int lo = a < b ? a : b, hi = a < b ? b : a;
    return lo * 33 + hi;
}

// ============ kA: stats partials + zero gram + stage weights ================
__global__ __launch_bounds__(256, 2)
void kA(const float* __restrict__ in, const float* __restrict__ W,
        const float* __restrict__ Wstat, float* __restrict__ ws) {
    int b = blockIdx.x, t = threadIdx.x;
    int idx = b * 256 + t;
    if (idx < 8960) ws[O_GRAMM + idx] = 0.f;          // 8 gram copies
    {                                                  // weights: 1 elt/thread
        int d = idx >> 5, j = idx & 31;
        ws[O_WSF + idx] = (j < 16) ? Wstat[d * 16 + j] : W[d * 16 + (j - 16)];
    }
    // stats: 4 colgroups x 128 rowgroups(32 rows); thread owns 4 cols
    int cgk = b & 3, rg = b >> 2;
    int c0 = cgk * 1024 + t * 4, r0 = rg * 32;
    float s0=0.f,s1=0.f,s2=0.f,s3=0.f,q0=0.f,q1=0.f,q2=0.f,q3=0.f;
    #pragma unroll 4
    for (int r = 0; r < 32; ++r) {
        float4 u = *(const float4*)&in[(size_t)(r0 + r) * DD + c0];
        s0 += u.x; q0 += u.x*u.x;  s1 += u.y; q1 += u.y*u.y;
        s2 += u.z; q2 += u.z*u.z;  s3 += u.w; q3 += u.w*u.w;
    }
    float* part = ws + O_PART + (size_t)rg * 8192;
    *(float4*)&part[c0]        = make_float4(s0, s1, s2, s3);
    *(float4*)&part[4096 + c0] = make_float4(q0, q1, q2, q3);
}

// ============ kB: finalize mu/inv per dgroup; normalized LDS GEMM ===========
// 512 blocks = 32 dgroups(128 d) x 16 rowgroups(256 rows); thread <-> row.
__global__ __launch_bounds__(256, 2)
void kB(const float* __restrict__ in, const float* __restrict__ ws,
        float* __restrict__ ypart) {
    __shared__ __align__(16) float tile[256 * 33];    // 33.8 KB
    __shared__ __align__(16) float mu_s[128];
    __shared__ __align__(16) float inv_s[128];
    __shared__ __align__(16) float muinv_s[128];
    int b = blockIdx.x, t = threadIdx.x;
    int dg = b & 31, rg = b >> 5;
    int dbase = dg * 128, rowbase = rg * 256;
    {   // prologue: reduce partials for this block's 128 cols (L2/L3-hot)
        int half = t >> 7, ci = t & 127;
        const float* p0 = ws + O_PART + (size_t)half * 4096 + dbase + ci;
        float a = 0.f;
        #pragma unroll 8
        for (int g = 0; g < 128; ++g) a += p0[(size_t)g * 8192];
        if (half == 0) mu_s[ci] = a * (1.0f / BB);
        __syncthreads();
        if (half == 1) {
            float m = mu_s[ci];
            float var = a * (1.0f / BB) - m * m; if (var < 0.f) var = 0.f;
            float iv = 1.0f / (sqrtf(var) + EPSF);
            inv_s[ci] = iv; muinv_s[ci] = m * iv;
        }
        __syncthreads();
    }
    float acc[32];
    #pragma unroll
    for (int i = 0; i < 32; ++i) acc[i] = 0.f;
    int c = t & 7, rr = t >> 3;                       // staging: chunk, row
    const float* wsf = ws + O_WSF;
    for (int stage = 0; stage < 4; ++stage) {
        int ds0 = stage * 32;                         // local d-offset
        float4 iv4 = *(const float4*)&inv_s[ds0 + c * 4];
        float4 mi4 = *(const float4*)&muinv_s[ds0 + c * 4];
        #pragma unroll
        for (int s = 0; s < 8; ++s) {                 // 8 sweeps x 32 rows
            int row = s * 32 + rr;
            float4 u = *(const float4*)&in[(size_t)(rowbase + row) * DD + dbase + ds0 + c * 4];
            int base = row * 33 + c * 4;              // normalize in staging
            tile[base + 0] = u.x * iv4.x - mi4.x;
            tile[base + 1] = u.y * iv4.y - mi4.y;
            tile[base + 2] = u.z * iv4.z - mi4.z;
            tile[base + 3] = u.w * iv4.w - mi4.w;
        }
        __syncthreads();
        const float* trow = tile + t * 33;
        #pragma unroll 4
        for (int dl = 0; dl < 32; ++dl) {
            float xs = trow[dl];
            const float* wr = wsf + (size_t)(dbase + ds0 + dl) * 32;  // uniform -> s_load
            #pragma unroll
            for (int j = 0; j < 32; ++j) acc[j] += xs * wr[j];
        }
        __syncthreads();
    }
    float* dst = ypart + ((size_t)dg * BB + rowbase + t) * 32;
    #pragma unroll
    for (int j = 0; j < 32; j += 4)
        *(float4*)(dst + j) = make_float4(acc[j], acc[j+1], acc[j+2], acc[j+3]);
}

// ============ kC: reduce ypart -> yz; gram atomics (8-way split) ============
__global__ __launch_bounds__(256, 2)
void kC(float* __restrict__ ws) {
    __shared__ float yz_s[8 * 34];
    int b = blockIdx.x, t = threadIdx.x;
    int rowbase = b * 8;                              // 512 blocks x 8 rows
    int r = t >> 5, c = t & 31;
    const float* yp = ws + O_YPART;
    size_t off = (size_t)(rowbase + r) * 32 + c;
    float s = 0.f;
    #pragma unroll
    for (int dg = 0; dg < 32; ++dg) s += yp[(size_t)dg * (BB * 32) + off];
    ws[O_YZ + off] = s;
    yz_s[r * 34 + c] = s;
    if (c == 0) yz_s[r * 34 + 32] = 1.0f;
    __syncthreads();
    float* gm = ws + O_GRAMM + (size_t)(b & 7) * 1120;
    for (int p = t; p < 561; p += 256) {              // upper-tri pairs i<=j<=32
        int i = 0, rem = p;
        while (rem >= 33 - i) { rem -= 33 - i; ++i; }
        int j = i + rem;
        float a2 = 0.f;
        #pragma unroll
        for (int r2 = 0; r2 < 8; ++r2) a2 += yz_s[r2 * 34 + i] * yz_s[r2 * 34 + j];
        atomicAdd(&gm[i * 33 + j], a2);
    }
}

// ============ kE: barriered 17-dim solve (redundant/block) + epilogue =======
// Basis p=0..15 -> Y[:,p], p=16 -> ones. Gram cols: Y->p, Z_t->16+t, 1->32.
__global__ __launch_bounds__(256, 2)
void kE(const float* __restrict__ ws, float* __restrict__ out) {
    __shared__ __align__(16) float yzs[64 * 36];      // 64 rows of [Y|Z]
    __shared__ float GA[17 * 17], gz[17 * 16], v[15][17], gad[15][16],
                     gzd[15][16], gu[17], u[17], st[2], wm[17 * 16];
    int b = blockIdx.x, t = threadIdx.x;
    int rowbase = b * 64;                             // 64 blocks x 64 rows
    // stage this block's 64 rows of [Y|Z] (512 float4, 2/thread)
    const float4* src = (const float4*)(ws + O_YZ) + (size_t)rowbase * 8;
    #pragma unroll
    for (int k = 0; k < 2; ++k) {
        int idx = k * 256 + t;
        float4 f = src[idx];
        int row = idx >> 3, c4 = (idx & 7) * 4;
        yzs[row * 36 + c4 + 0] = f.x; yzs[row * 36 + c4 + 1] = f.y;
        yzs[row * 36 + c4 + 2] = f.z; yzs[row * 36 + c4 + 3] = f.w;
    }
    // gram (sum of 8 copies) -> LDS, all threads
    const float* gm = ws + O_GRAMM;
    for (int idx = t; idx < 17 * 17; idx += 256) {
        int p = idx / 17, q = idx % 17;
        int gi = gidx(p < 16 ? p : 32, q < 16 ? q : 32);
        float s = 0.f;
        #pragma unroll
        for (int m = 0; m < 8; ++m) s += gm[m * 1120 + gi];
        GA[idx] = s;
    }
    for (int idx = t; idx < 17 * 16; idx += 256) {
        int p = idx / 16, tt = idx % 16;
        int gi = gidx(p < 16 ? p : 32, 16 + tt);
        float s = 0.f;
        #pragma unroll
        for (int m = 0; m < 8; ++m) s += gm[m * 1120 + gi];
        gz[idx] = s;
    }
    if (t < 17) u[t] = (t == 0) ? 1.f : 0.f;
    __syncthreads();
    const float invB = 1.0f / BB;
    for (int i = 0; i < 15; ++i) {
        if (t < 17) {                                 // gu = GA @ u
            float s = 0.f;
            for (int q = 0; q < 17; ++q) s += GA[t * 17 + q] * u[q];
            gu[t] = s;
        }
        __syncthreads();
        if (t == 0) {                                 // stats of c_i
            float mean = gu[16] * invB, e2 = 0.f;
            for (int p = 0; p < 17; ++p) e2 += u[p] * gu[p];
            e2 *= invB;
            float var = e2 - mean * mean; if (var < 0.f) var = 0.f;
            st[0] = mean; st[1] = 1.0f / (sqrtf(var) + EPSF);
        }
        __syncthreads();
        if (t < 17) v[i][t] = (u[t] - (t == 16 ? st[0] : 0.f)) * st[1];
        __syncthreads();
        if (t < 16) {                                 // conv_i . Y[:,k]
            float s = 0.f;
            for (int p = 0; p < 17; ++p) s += v[i][p] * GA[p * 17 + t];
            gad[i][t] = s;
        } else if (t < 32) {                          // conv_i . Z[:,tt]
            int tt = t - 16;
            float s = 0.f;
            for (int p = 0; p < 17; ++p) s += v[i][p] * gz[p * 16 + tt];
            gzd[i][tt] = s;
        }
        __syncthreads();
        if (t < 17) {                                 // u_{i+1}
            float a2 = 0.f;
            for (int j = 0; j <= i; ++j) a2 += v[j][t] * gad[j][i + 1];
            u[t] = ((t == i + 1) ? 1.f : 0.f) - a2 * invB;
        }
        __syncthreads();
    }
    for (int idx = t; idx < 17 * 16; idx += 256) {
        int p = idx / 16, tt = idx % 16;
        float s = 0.f;
        for (int j = 0; j < tt; ++j) s += v[j][p] * gzd[j][tt];
        wm[idx] = s * invB;
    }
    __syncthreads();
    // epilogue: 4 outputs/thread, coalesced float4 store
    int row = t >> 2, c0 = (t & 3) * 4;
    const float* yr = yzs + row * 36;
    float o[4];
    #pragma unroll
    for (int k = 0; k < 4; ++k) o[k] = yr[16 + c0 + k] - wm[16 * 16 + c0 + k];
    #pragma unroll
    for (int p = 0; p < 16; ++p) {
        float yp = yr[p];
        #pragma unroll
        for (int k = 0; k < 4; ++k) o[k] -= yp * wm[p * 16 + c0 + k];
    }
    *(float4*)&out[(size_t)rowbase * 16 + t * 4] = make_float4(o[0], o[1], o[2], o[3]);
}

extern "C" void kernel_launch(void* const* d_in, const int* in_sizes, int n_in,
                              void* d_out, int out_size, void* d_ws, size_t ws_size,
                              hipStream_t stream) {
    const float* in    = (const float*)d_in[0];
    const float* W     = (const float*)d_in[1];
    const float* Wstat = (const float*)d_in[2];
    float* ws  = (float*)d_ws;
    float* out = (float*)d_out;

    kA<<<dim3(512), dim3(256), 0, stream>>>(in, W, Wstat, ws);
    kB<<<dim3(512), dim3(256), 0, stream>>>(in, ws, ws + O_YPART);
    kC<<<dim3(512), dim3(256), 0, stream>>>(ws);
    kE<<<dim3(64),  dim3(256), 0, stream>>>(ws, out);
}

// Round 6
// 165.084 us; speedup vs baseline: 1.2263x; 1.0060x over previous
//
#include <hip/hip_runtime.h>
#include <stdint.h>

// FactorLayer: B=4096, D=4096, T=16, float32.
// X = znorm(inputs); Y = X@W_static; Z = X@W. All deflations use ORIGINAL X,
// so conv_j is fixed once born; everything lives in span{Y0..Y15, 1}.
// Sequential scan collapses to 17-dim recurrences on the Gram of [Y|Z|1];
// Out = Z - [Y|1] @ Wmat (17x16).  4 plain launches.
// R3: cooperative launch silently no-ops in this harness.
// R5 (passed, 166us): kB = 41us, VALUBusy 18% (= 7.4us real VALU work),
//   FETCH 35MB (~10us mem) -> ~30us of barrier-serialized stall.
// R6: register-prefetch pipeline in kB (stage k+1 loads issued before stage k
//   compute). Only kB's staging loop changed vs R5.

#define BB 4096
#define DD 4096
#define EPSF 1e-6f

// ws layout (float indices), ~22 MB total
#define O_PART    0u          // [128 rowgroups][8192]: colsum(0..4095), colsq(4096..8191)
#define O_WSF     1048576u    // [d][32]: j<16 -> W_static (Y), j>=16 -> W (Z)
#define O_GRAMM   1179648u    // 8 copies x 1120 (33x33, upper-tri used)
#define O_YZ      1188608u    // [4096][32]  (byte offset 16B-aligned)
#define O_YPART   1319680u    // [32 dgroups][4096][32]

__device__ __forceinline__ int gidx(int a, int b) {   // upper-tri gram index
    int lo = a < b ? a : b, hi = a < b ? b : a;
    return lo * 33 + hi;
}

// ============ kA: stats partials + zero gram + stage weights ================
__global__ __launch_bounds__(256, 2)
void kA(const float* __restrict__ in, const float* __restrict__ W,
        const float* __restrict__ Wstat, float* __restrict__ ws) {
    int b = blockIdx.x, t = threadIdx.x;
    int idx = b * 256 + t;
    if (idx < 8960) ws[O_GRAMM + idx] = 0.f;          // 8 gram copies
    {                                                  // weights: 1 elt/thread
        int d = idx >> 5, j = idx & 31;
        ws[O_WSF + idx] = (j < 16) ? Wstat[d * 16 + j] : W[d * 16 + (j - 16)];
    }
    // stats: 4 colgroups x 128 rowgroups(32 rows); thread owns 4 cols
    int cgk = b & 3, rg = b >> 2;
    int c0 = cgk * 1024 + t * 4, r0 = rg * 32;
    float s0=0.f,s1=0.f,s2=0.f,s3=0.f,q0=0.f,q1=0.f,q2=0.f,q3=0.f;
    #pragma unroll 4
    for (int r = 0; r < 32; ++r) {
        float4 u = *(const float4*)&in[(size_t)(r0 + r) * DD + c0];
        s0 += u.x; q0 += u.x*u.x;  s1 += u.y; q1 += u.y*u.y;
        s2 += u.z; q2 += u.z*u.z;  s3 += u.w; q3 += u.w*u.w;
    }
    float* part = ws + O_PART + (size_t)rg * 8192;
    *(float4*)&part[c0]        = make_float4(s0, s1, s2, s3);
    *(float4*)&part[4096 + c0] = make_float4(q0, q1, q2, q3);
}

// ============ kB: finalize mu/inv per dgroup; pipelined normalized GEMM =====
// 512 blocks = 32 dgroups(128 d) x 16 rowgroups(256 rows); thread <-> row.
__global__ __launch_bounds__(256, 2)
void kB(const float* __restrict__ in, const float* __restrict__ ws,
        float* __restrict__ ypart) {
    __shared__ __align__(16) float tile[256 * 33];    // 33.8 KB
    __shared__ __align__(16) float mu_s[128];
    __shared__ __align__(16) float inv_s[128];
    __shared__ __align__(16) float muinv_s[128];
    int b = blockIdx.x, t = threadIdx.x;
    int dg = b & 31, rg = b >> 5;
    int dbase = dg * 128, rowbase = rg * 256;
    {   // prologue: reduce partials for this block's 128 cols (L2/L3-hot)
        int half = t >> 7, ci = t & 127;
        const float* p0 = ws + O_PART + (size_t)half * 4096 + dbase + ci;
        float a = 0.f;
        #pragma unroll 8
        for (int g = 0; g < 128; ++g) a += p0[(size_t)g * 8192];
        if (half == 0) mu_s[ci] = a * (1.0f / BB);
        __syncthreads();
        if (half == 1) {
            float m = mu_s[ci];
            float var = a * (1.0f / BB) - m * m; if (var < 0.f) var = 0.f;
            float iv = 1.0f / (sqrtf(var) + EPSF);
            inv_s[ci] = iv; muinv_s[ci] = m * iv;
        }
        __syncthreads();
    }
    float acc[32];
    #pragma unroll
    for (int i = 0; i < 32; ++i) acc[i] = 0.f;
    int c = t & 7, rr = t >> 3;                       // staging: chunk, row
    const float* wsf = ws + O_WSF;
    const float* inrow = in + (size_t)rowbase * DD + dbase + c * 4;
    float4 pf[8];                                     // register prefetch buffer
    #pragma unroll
    for (int s = 0; s < 8; ++s)                       // preload stage 0
        pf[s] = *(const float4*)&inrow[(size_t)(s * 32 + rr) * DD];
    for (int stage = 0; stage < 4; ++stage) {
        int ds0 = stage * 32;                         // local d-offset
        float4 iv4 = *(const float4*)&inv_s[ds0 + c * 4];
        float4 mi4 = *(const float4*)&muinv_s[ds0 + c * 4];
        #pragma unroll
        for (int s = 0; s < 8; ++s) {                 // regs -> LDS, normalized
            int base = (s * 32 + rr) * 33 + c * 4;
            tile[base + 0] = pf[s].x * iv4.x - mi4.x;
            tile[base + 1] = pf[s].y * iv4.y - mi4.y;
            tile[base + 2] = pf[s].z * iv4.z - mi4.z;
            tile[base + 3] = pf[s].w * iv4.w - mi4.w;
        }
        __syncthreads();
        if (stage < 3) {                              // issue next stage's loads
            #pragma unroll
            for (int s = 0; s < 8; ++s)
                pf[s] = *(const float4*)&inrow[(size_t)(s * 32 + rr) * DD + (stage + 1) * 32];
        }
        const float* trow = tile + t * 33;            // compute current stage
        #pragma unroll 4
        for (int dl = 0; dl < 32; ++dl) {
            float xs = trow[dl];
            const float* wr = wsf + (size_t)(dbase + ds0 + dl) * 32;  // uniform -> s_load
            #pragma unroll
            for (int j = 0; j < 32; ++j) acc[j] += xs * wr[j];
        }
        __syncthreads();
    }
    float* dst = ypart + ((size_t)dg * BB + rowbase + t) * 32;
    #pragma unroll
    for (int j = 0; j < 32; j += 4)
        *(float4*)(dst + j) = make_float4(acc[j], acc[j+1], acc[j+2], acc[j+3]);
}

// ============ kC: reduce ypart -> yz; gram atomics (8-way split) ============
__global__ __launch_bounds__(256, 2)
void kC(float* __restrict__ ws) {
    __shared__ float yz_s[8 * 34];
    int b = blockIdx.x, t = threadIdx.x;
    int rowbase = b * 8;                              // 512 blocks x 8 rows
    int r = t >> 5, c = t & 31;
    const float* yp = ws + O_YPART;
    size_t off = (size_t)(rowbase + r) * 32 + c;
    float s = 0.f;
    #pragma unroll
    for (int dg = 0; dg < 32; ++dg) s += yp[(size_t)dg * (BB * 32) + off];
    ws[O_YZ + off] = s;
    yz_s[r * 34 + c] = s;
    if (c == 0) yz_s[r * 34 + 32] = 1.0f;
    __syncthreads();
    float* gm = ws + O_GRAMM + (size_t)(b & 7) * 1120;
    for (int p = t; p < 561; p += 256) {              // upper-tri pairs i<=j<=32
        int i = 0, rem = p;
        while (rem >= 33 - i) { rem -= 33 - i; ++i; }
        int j = i + rem;
        float a2 = 0.f;
        #pragma unroll
        for (int r2 = 0; r2 < 8; ++r2) a2 += yz_s[r2 * 34 + i] * yz_s[r2 * 34 + j];
        atomicAdd(&gm[i * 33 + j], a2);
    }
}

// ============ kE: barriered 17-dim solve (redundant/block) + epilogue =======
// Basis p=0..15 -> Y[:,p], p=16 -> ones. Gram cols: Y->p, Z_t->16+t, 1->32.
__global__ __launch_bounds__(256, 2)
void kE(const float* __restrict__ ws, float* __restrict__ out) {
    __shared__ __align__(16) float yzs[64 * 36];      // 64 rows of [Y|Z]
    __shared__ float GA[17 * 17], gz[17 * 16], v[15][17], gad[15][16],
                     gzd[15][16], gu[17], u[17], st[2], wm[17 * 16];
    int b = blockIdx.x, t = threadIdx.x;
    int rowbase = b * 64;                             // 64 blocks x 64 rows
    // stage this block's 64 rows of [Y|Z] (512 float4, 2/thread)
    const float4* src = (const float4*)(ws + O_YZ) + (size_t)rowbase * 8;
    #pragma unroll
    for (int k = 0; k < 2; ++k) {
        int idx = k * 256 + t;
        float4 f = src[idx];
        int row = idx >> 3, c4 = (idx & 7) * 4;
        yzs[row * 36 + c4 + 0] = f.x; yzs[row * 36 + c4 + 1] = f.y;
        yzs[row * 36 + c4 + 2] = f.z; yzs[row * 36 + c4 + 3] = f.w;
    }
    // gram (sum of 8 copies) -> LDS, all threads
    const float* gm = ws + O_GRAMM;
    for (int idx = t; idx < 17 * 17; idx += 256) {
        int p = idx / 17, q = idx % 17;
        int gi = gidx(p < 16 ? p : 32, q < 16 ? q : 32);
        float s = 0.f;
        #pragma unroll
        for (int m = 0; m < 8; ++m) s += gm[m * 1120 + gi];
        GA[idx] = s;
    }
    for (int idx = t; idx < 17 * 16; idx += 256) {
        int p = idx / 16, tt = idx % 16;
        int gi = gidx(p < 16 ? p : 32, 16 + tt);
        float s = 0.f;
        #pragma unroll
        for (int m = 0; m < 8; ++m) s += gm[m * 1120 + gi];
        gz[idx] = s;
    }
    if (t < 17) u[t] = (t == 0) ? 1.f : 0.f;
    __syncthreads();
    const float invB = 1.0f / BB;
    for (int i = 0; i < 15; ++i) {
        if (t < 17) {                                 // gu = GA @ u
            float s = 0.f;
            for (int q = 0; q < 17; ++q) s += GA[t * 17 + q] * u[q];
            gu[t] = s;
        }
        __syncthreads();
        if (t == 0) {                                 // stats of c_i
            float mean = gu[16] * invB, e2 = 0.f;
            for (int p = 0; p < 17; ++p) e2 += u[p] * gu[p];
            e2 *= invB;
            float var = e2 - mean * mean; if (var < 0.f) var = 0.f;
            st[0] = mean; st[1] = 1.0f / (sqrtf(var) + EPSF);
        }
        __syncthreads();
        if (t < 17) v[i][t] = (u[t] - (t == 16 ? st[0] : 0.f)) * st[1];
        __syncthreads();
        if (t < 16) {                                 // conv_i . Y[:,k]
            float s = 0.f;
            for (int p = 0; p < 17; ++p) s += v[i][p] * GA[p * 17 + t];
            gad[i][t] = s;
        } else if (t < 32) {                          // conv_i . Z[:,tt]
            int tt = t - 16;
            float s = 0.f;
            for (int p = 0; p < 17; ++p) s += v[i][p] * gz[p * 16 + tt];
            gzd[i][tt] = s;
        }
        __syncthreads();
        if (t < 17) {                                 // u_{i+1}
            float a2 = 0.f;
            for (int j = 0; j <= i; ++j) a2 += v[j][t] * gad[j][i + 1];
            u[t] = ((t == i + 1) ? 1.f : 0.f) - a2 * invB;
        }
        __syncthreads();
    }
    for (int idx = t; idx < 17 * 16; idx += 256) {
        int p = idx / 16, tt = idx % 16;
        float s = 0.f;
        for (int j = 0; j < tt; ++j) s += v[j][p] * gzd[j][tt];
        wm[idx] = s * invB;
    }
    __syncthreads();
    // epilogue: 4 outputs/thread, coalesced float4 store
    int row = t >> 2, c0 = (t & 3) * 4;
    const float* yr = yzs + row * 36;
    float o[4];
    #pragma unroll
    for (int k = 0; k < 4; ++k) o[k] = yr[16 + c0 + k] - wm[16 * 16 + c0 + k];
    #pragma unroll
    for (int p = 0; p < 16; ++p) {
        float yp = yr[p];
        #pragma unroll
        for (int k = 0; k < 4; ++k) o[k] -= yp * wm[p * 16 + c0 + k];
    }
    *(float4*)&out[(size_t)rowbase * 16 + t * 4] = make_float4(o[0], o[1], o[2], o[3]);
}

extern "C" void kernel_launch(void* const* d_in, const int* in_sizes, int n_in,
                              void* d_out, int out_size, void* d_ws, size_t ws_size,
                              hipStream_t stream) {
    const float* in    = (const float*)d_in[0];
    const float* W     = (const float*)d_in[1];
    const float* Wstat = (const float*)d_in[2];
    float* ws  = (float*)d_ws;
    float* out = (float*)d_out;

    kA<<<dim3(512), dim3(256), 0, stream>>>(in, W, Wstat, ws);
    kB<<<dim3(512), dim3(256), 0, stream>>>(in, ws, ws + O_YPART);
    kC<<<dim3(512), dim3(256), 0, stream>>>(ws);
    kE<<<dim3(64),  dim3(256), 0, stream>>>(ws, out);
}